// Round 4
// baseline (6449.412 us; speedup 1.0000x reference)
//
#include <hip/hip_runtime.h>

#define NN 30000
#define NE 400000

__constant__ int d_SRC[10] = {0,1,2,3,0,1,2,1,3,1};
__constant__ int d_DST[10] = {0,1,2,3,1,0,1,2,1,3};

// ---------------- fp32 tiled GEMM: C[M,N] = act(A)[M,K] @ B[K,N] + bias ----
// epi=0: store C (fp32). epi=1: tanh + column-sum -> atomicAdd into C[N] (colsum).
// relu_a: apply relu to A on load.
template<int BN>
__global__ __launch_bounds__(256)
void gemm_k(const float* __restrict__ A, long sA,
            const float* __restrict__ B, long sB,
            const float* __restrict__ bias, long sBias,
            float* __restrict__ C, long sC,
            int M, int K, int N, int relu_a, int epi)
{
    constexpr int BM = 64, BK = 16;
    constexpr int TN = BN / 16;
    const int z = blockIdx.z;
    A += (long)z * sA;
    B += (long)z * sB;
    bias += (long)z * sBias;
    C += (long)z * sC;
    const int m0 = blockIdx.x * BM;
    const int n0 = blockIdx.y * BN;
    const int tid = threadIdx.x;

    __shared__ float As[BK][BM];
    __shared__ float Bs[BK][BN];

    const int ar = tid >> 2;          // tile row for A load
    const int ak = (tid & 3) << 2;    // k offset (x4)
    const int bk = tid >> 4;          // tile k for B load
    const int bn = (tid & 15) * TN;   // col offset
    const int tr = (tid >> 4) << 2;   // acc row base
    const int tc = (tid & 15) * TN;   // acc col base

    float acc[4][TN];
#pragma unroll
    for (int r = 0; r < 4; ++r)
#pragma unroll
        for (int j = 0; j < TN; ++j) acc[r][j] = 0.f;

    const int grow = m0 + ar;
    for (int k0 = 0; k0 < K; k0 += BK) {
        float av[4];
        if (grow < M) {
            const float* ap = A + (long)grow * K + k0 + ak;
            float4 u = *(const float4*)ap;
            av[0] = u.x; av[1] = u.y; av[2] = u.z; av[3] = u.w;
            if (relu_a) {
#pragma unroll
                for (int j = 0; j < 4; ++j) av[j] = fmaxf(av[j], 0.f);
            }
        } else {
            av[0] = av[1] = av[2] = av[3] = 0.f;
        }
        As[ak + 0][ar] = av[0]; As[ak + 1][ar] = av[1];
        As[ak + 2][ar] = av[2]; As[ak + 3][ar] = av[3];

        {
            const float* bp = B + (long)(k0 + bk) * N + n0 + bn;
            if constexpr (TN == 4) {
                float4 u = *(const float4*)bp;
                Bs[bk][bn + 0] = u.x; Bs[bk][bn + 1] = u.y;
                Bs[bk][bn + 2] = u.z; Bs[bk][bn + 3] = u.w;
            } else {
                float2 u = *(const float2*)bp;
                Bs[bk][bn + 0] = u.x; Bs[bk][bn + 1] = u.y;
            }
        }
        __syncthreads();
#pragma unroll
        for (int k = 0; k < BK; ++k) {
            float4 a4 = *(const float4*)&As[k][tr];
            float ar4[4] = {a4.x, a4.y, a4.z, a4.w};
            float bv[TN];
            if constexpr (TN == 4) {
                float4 b4 = *(const float4*)&Bs[k][tc];
                bv[0] = b4.x; bv[1] = b4.y; bv[2] = b4.z; bv[3] = b4.w;
            } else {
                float2 b2 = *(const float2*)&Bs[k][tc];
                bv[0] = b2.x; bv[1] = b2.y;
            }
#pragma unroll
            for (int r = 0; r < 4; ++r)
#pragma unroll
                for (int j = 0; j < TN; ++j)
                    acc[r][j] += ar4[r] * bv[j];
        }
        __syncthreads();
    }

    float biasv[TN];
#pragma unroll
    for (int j = 0; j < TN; ++j) biasv[j] = bias[n0 + tc + j];

    if (epi == 0) {
#pragma unroll
        for (int r = 0; r < 4; ++r) {
            int gr = m0 + tr + r;
            if (gr < M) {
                float* cp = C + (long)gr * N + n0 + tc;
#pragma unroll
                for (int j = 0; j < TN; ++j) cp[j] = acc[r][j] + biasv[j];
            }
        }
    } else {
        float cs[TN];
#pragma unroll
        for (int j = 0; j < TN; ++j) cs[j] = 0.f;
#pragma unroll
        for (int r = 0; r < 4; ++r) {
            int gr = m0 + tr + r;
            if (gr < M) {
#pragma unroll
                for (int j = 0; j < TN; ++j) cs[j] += tanhf(acc[r][j] + biasv[j]);
            }
        }
        float* red = &As[0][0];  // reuse LDS (post-loop sync already done)
#pragma unroll
        for (int j = 0; j < TN; ++j) red[(tid >> 4) * BN + tc + j] = cs[j];
        __syncthreads();
        if (tid < BN) {
            float s = 0.f;
            for (int t16 = 0; t16 < 16; ++t16) s += red[t16 * BN + tid];
            unsafeAtomicAdd(&C[n0 + tid], s);
        }
    }
}

// ---------------- layer-1 attention dots: asrc/adst [10][NN][8] ----------------
__global__ __launch_bounds__(256)
void attn_dots1(const float* __restrict__ h1,
                const float* __restrict__ att_src,
                const float* __restrict__ att_dst,
                float* __restrict__ asrc, float* __restrict__ adst)
{
    int gid = blockIdx.x * 256 + threadIdx.x;
    int wave = gid >> 6;
    int lane = gid & 63;
    if (wave >= 10 * NN) return;
    int e = wave / NN;
    int n = wave - e * NN;
    int s = d_SRC[e], d = d_DST[e];
    float2 hs = *(const float2*)&h1[(long)(s * NN + n) * 128 + 2 * lane];
    float2 hd = *(const float2*)&h1[(long)(d * NN + n) * 128 + 2 * lane];
    float2 av = *(const float2*)&att_src[e * 128 + 2 * lane];
    float2 bv = *(const float2*)&att_dst[e * 128 + 2 * lane];
    float ps = hs.x * av.x + hs.y * av.y;
    float pd = hd.x * bv.x + hd.y * bv.y;
#pragma unroll
    for (int off = 1; off < 8; off <<= 1) {
        ps += __shfl_xor(ps, off, 64);
        pd += __shfl_xor(pd, off, 64);
    }
    if ((lane & 7) == 0) {
        int h = lane >> 3;
        asrc[(long)(e * NN + n) * 8 + h] = ps;
        adst[(long)(e * NN + n) * 8 + h] = pd;
    }
}

// ---------------- layer-1 denom: atomic sum of exp(leaky(alpha)) per (dst,head) -------
__global__ __launch_bounds__(256)
void edge_denom1(const int* __restrict__ edges,
                 const float* __restrict__ asrc, const float* __restrict__ adst,
                 float* __restrict__ denom)
{
    int idx = blockIdx.x * 256 + threadIdx.x;
    if (idx >= 10 * NE) return;
    int e = idx / NE;
    int i = idx - e * NE;
    int row = edges[(long)e * 2 * NE + i];
    int col = edges[(long)e * 2 * NE + NE + i];
    const float* as = &asrc[(long)(e * NN + row) * 8];
    const float* ad = &adst[(long)(e * NN + col) * 8];
    float* dn = &denom[(long)(e * NN + col) * 8];
#pragma unroll
    for (int h = 0; h < 8; ++h) {
        float a = as[h] + ad[h];
        a = a > 0.f ? a : 0.2f * a;
        unsafeAtomicAdd(&dn[h], __expf(a));
    }
}

// ---------------- layer-1 message scatter for ONE relation into one agg slot ----------
__global__ __launch_bounds__(256)
void edge_msg1_rel(const int* __restrict__ edges_e,   // edges + e*2*NE
                   const float* __restrict__ h1s,     // h1 + s*NN*128
                   const float* __restrict__ asrc_e,  // asrc1 + e*NN*8
                   const float* __restrict__ adst_e,
                   const float* __restrict__ denom_e,
                   float* __restrict__ slot)          // [NN][128]
{
    long gid = (long)blockIdx.x * 256 + threadIdx.x;
    int lane = (int)(gid & 63);
    int i = (int)(gid >> 6);
    if (i >= NE) return;
    int row = edges_e[i];
    int col = edges_e[NE + i];
    int h = lane >> 3;
    float a = asrc_e[row * 8 + h] + adst_e[col * 8 + h];
    a = a > 0.f ? a : 0.2f * a;
    float w = __expf(a) / (denom_e[col * 8 + h] + 1e-16f);
    float2 hv = *(const float2*)&h1s[(long)row * 128 + 2 * lane];
    float* ap = &slot[(long)col * 128 + 2 * lane];
    unsafeAtomicAdd(ap, hv.x * w);
    unsafeAtomicAdd(ap + 1, hv.y * w);
}

// ---------------- semantic score softmax for ONE dst type ----------------
__global__ void score_t_k(const float* __restrict__ colsum, const float* __restrict__ q,
                          float* __restrict__ sattn, int C, int t)
{
    __shared__ float sc[10];
    int tid = threadIdx.x;
    if (tid < 10) {
        if (d_DST[tid] == t) {
            float s = 0.f;
            for (int c = 0; c < C; ++c) s += q[c] * colsum[tid * C + c];
            sc[tid] = s / (float)NN;
        } else {
            sc[tid] = -1e30f;
        }
    }
    __syncthreads();
    if (tid == 0) {
        float mx = -1e30f;
        for (int m = 0; m < 10; ++m) if (d_DST[m] == t) mx = fmaxf(mx, sc[m]);
        float sum = 0.f;
        float ex[10];
        for (int m = 0; m < 10; ++m) {
            ex[m] = 0.f;
            if (d_DST[m] == t) { ex[m] = __expf(sc[m] - mx); sum += ex[m]; }
        }
        for (int m = 0; m < 10; ++m) if (d_DST[m] == t) sattn[m] = ex[m] / sum;
    }
}

// ---------------- per-type fusion: out = elu( sum_j sattn[r_j]*relu(slot_j) ) ---------
// out may alias one of the input slots (elementwise in-place is race-free).
__global__ __launch_bounds__(256)
void fusion_t(const float* s0, const float* s1, const float* s2, const float* s3,
              int cnt, int r0, int r1, int r2, int r3,
              const float* __restrict__ sattn, float* __restrict__ out)
{
    int idx = blockIdx.x * 256 + threadIdx.x;
    if (idx >= NN * 32) return;
    int c4 = idx & 31;
    int n = idx >> 5;
    long off = (long)n * 128 + c4 * 4;
    const float* sl[4] = {s0, s1, s2, s3};
    int rl[4] = {r0, r1, r2, r3};
    float4 o = {0.f, 0.f, 0.f, 0.f};
    for (int j = 0; j < cnt; ++j) {
        float w = sattn[rl[j]];
        float4 v = *(const float4*)(sl[j] + off);
        o.x += w * fmaxf(v.x, 0.f);
        o.y += w * fmaxf(v.y, 0.f);
        o.z += w * fmaxf(v.z, 0.f);
        o.w += w * fmaxf(v.w, 0.f);
    }
    o.x = o.x > 0.f ? o.x : __expf(o.x) - 1.f;
    o.y = o.y > 0.f ? o.y : __expf(o.y) - 1.f;
    o.z = o.z > 0.f ? o.z : __expf(o.z) - 1.f;
    o.w = o.w > 0.f ? o.w : __expf(o.w) - 1.f;
    *(float4*)(out + off) = o;
}

// ---------------- layer-2 attention dots (1 head, 32 ch) ----------------
__global__ __launch_bounds__(256)
void attn_dots2(const float* __restrict__ h2,
                const float* __restrict__ att_src,
                const float* __restrict__ att_dst,
                float* __restrict__ asrc, float* __restrict__ adst)
{
    int gid = blockIdx.x * 256 + threadIdx.x;
    int p = gid >> 5;
    int l = gid & 31;
    if (p >= 10 * NN) return;
    int e = p / NN, n = p - e * NN;
    int s = d_SRC[e], d = d_DST[e];
    float hs = h2[(long)(s * NN + n) * 32 + l];
    float hd = h2[(long)(d * NN + n) * 32 + l];
    float ps = hs * att_src[e * 32 + l];
    float pd = hd * att_dst[e * 32 + l];
#pragma unroll
    for (int off = 1; off < 32; off <<= 1) {
        ps += __shfl_xor(ps, off, 64);
        pd += __shfl_xor(pd, off, 64);
    }
    if (l == 0) { asrc[e * NN + n] = ps; adst[e * NN + n] = pd; }
}

__global__ __launch_bounds__(256)
void edge_denom2(const int* __restrict__ edges,
                 const float* __restrict__ asrc, const float* __restrict__ adst,
                 float* __restrict__ denom)
{
    int idx = blockIdx.x * 256 + threadIdx.x;
    if (idx >= 10 * NE) return;
    int e = idx / NE;
    int i = idx - e * NE;
    int row = edges[(long)e * 2 * NE + i];
    int col = edges[(long)e * 2 * NE + NE + i];
    float a = asrc[e * NN + row] + adst[e * NN + col];
    a = a > 0.f ? a : 0.2f * a;
    unsafeAtomicAdd(&denom[e * NN + col], __expf(a));
}

__global__ __launch_bounds__(256)
void edge_msg2(const int* __restrict__ edges,
               const float* __restrict__ h2,
               const float* __restrict__ asrc, const float* __restrict__ adst,
               const float* __restrict__ denom,
               float* __restrict__ agg)
{
    long gid = (long)blockIdx.x * 256 + threadIdx.x;
    int c = (int)(gid & 31);
    long eg = gid >> 5;
    if (eg >= (long)10 * NE) return;
    int e = (int)(eg / NE);
    int i = (int)(eg - (long)e * NE);
    int row = edges[(long)e * 2 * NE + i];
    int col = edges[(long)e * 2 * NE + NE + i];
    int s = d_SRC[e];
    float a = asrc[e * NN + row] + adst[e * NN + col];
    a = a > 0.f ? a : 0.2f * a;
    float w = __expf(a) / (denom[e * NN + col] + 1e-16f);
    float hv = h2[(long)(s * NN + row) * 32 + c];
    unsafeAtomicAdd(&agg[(long)(e * NN + col) * 32 + c], hv * w);
}

// ---------------- semantic score + softmax over ALL types (layer 2) ----------------
__global__ void score_all_k(const float* __restrict__ colsum, const float* __restrict__ q,
                            float* __restrict__ sattn, int C)
{
    __shared__ float sc[10];
    int tid = threadIdx.x;
    if (tid < 10) {
        float s = 0.f;
        for (int c = 0; c < C; ++c) s += q[c] * colsum[tid * C + c];
        sc[tid] = s / (float)NN;
    }
    __syncthreads();
    if (tid < 4) {
        float mx = -1e30f;
        for (int m = 0; m < 10; ++m) if (d_DST[m] == tid) mx = fmaxf(mx, sc[m]);
        float ex[10];
        float sum = 0.f;
        for (int m = 0; m < 10; ++m) {
            ex[m] = 0.f;
            if (d_DST[m] == tid) { ex[m] = __expf(sc[m] - mx); sum += ex[m]; }
        }
        for (int m = 0; m < 10; ++m) if (d_DST[m] == tid) sattn[m] = ex[m] / sum;
    }
}

// ---------------- final: per-node channel softmax, fp32 out ----------------
__global__ __launch_bounds__(256)
void final_softmax(const float* __restrict__ agg, const float* __restrict__ sattn,
                   float* __restrict__ out)
{
    int gid = blockIdx.x * 256 + threadIdx.x;
    int c = gid & 31;
    int p = gid >> 5;
    if (p >= 4 * NN) return;
    int t = p / NN, n = p - t * NN;
    float f = 0.f;
    for (int m = 0; m < 10; ++m) {
        if (d_DST[m] != t) continue;
        f += sattn[m] * fmaxf(agg[(long)(m * NN + n) * 32 + c], 0.f);
    }
    float mx = f;
#pragma unroll
    for (int off = 1; off < 32; off <<= 1) mx = fmaxf(mx, __shfl_xor(mx, off, 64));
    float ex = __expf(f - mx);
    float sm = ex;
#pragma unroll
    for (int off = 1; off < 32; off <<= 1) sm += __shfl_xor(sm, off, 64);
    out[(long)(t * NN + n) * 32 + c] = ex / sm;
}

extern "C" void kernel_launch(void* const* d_in, const int* in_sizes, int n_in,
                              void* d_out, int out_size, void* d_ws, size_t ws_size,
                              hipStream_t stream) {
    const float* x[4] = {
        (const float*)d_in[0], (const float*)d_in[1],
        (const float*)d_in[2], (const float*)d_in[3]};
    const int* edges = (const int*)d_in[4];
    const float* W1    = (const float*)d_in[5];
    const float* b1    = (const float*)d_in[6];
    const float* att1s = (const float*)d_in[7];
    const float* att1d = (const float*)d_in[8];
    const float* k1W   = (const float*)d_in[9];
    const float* k1b   = (const float*)d_in[10];
    const float* q1    = (const float*)d_in[11];
    const float* W2    = (const float*)d_in[12];
    const float* b2    = (const float*)d_in[13];
    const float* att2s = (const float*)d_in[14];
    const float* att2d = (const float*)d_in[15];
    const float* k2W   = (const float*)d_in[16];
    const float* k2b   = (const float*)d_in[17];
    const float* q2    = (const float*)d_in[18];

    // ---- workspace layout (floats), peak ~167 MB ----
    float* W = (float*)d_ws;
    float* h1      = W;                      // 15,360,000  (layer-2 overlays here later)
    float* slots   = W + 15360000;           // 5 x 3,840,000 = 19,200,000
    float* asrc1   = W + 34560000;           //  2,400,000
    float* adst1   = W + 36960000;           //  2,400,000
    float* denom1  = W + 39360000;           //  2,400,000
    float* colsum1 = W + 41760000;           //      1,280
    float* sattn1  = W + 41761280;           //         16
    float* colsum2 = W + 41761296;           //        320
    float* sattn2  = W + 41761616;           //         16
    // layer-2 overlay into h1's region (h1 dead after last edge_msg1_rel):
    float* h2      = h1;                     //  3,840,000
    float* agg2    = h1 + 3840000;           //  9,600,000
    float* asrc2   = h1 + 13440000;          //    300,000
    float* adst2   = h1 + 13740000;          //    300,000
    float* denom2  = h1 + 14040000;          //    300,000

    const long SLOT = 3840000;  // NN*128
    auto slot_p = [&](int i) { return slots + (long)i * SLOT; };

    hipMemsetAsync(denom1, 0, 2400000L * 4, stream);
    hipMemsetAsync(colsum1, 0, 1632L * 4, stream);

    // layer-1 projection: h1[t] = x[t] @ W1[t] + b1[t]
    for (int t = 0; t < 4; ++t) {
        gemm_k<64><<<dim3(469, 2, 1), 256, 0, stream>>>(
            x[t], 0, W1 + (long)t * 256 * 128, 0, b1 + t * 128, 0,
            h1 + (long)t * NN * 128, 0, NN, 256, 128, 0, 0);
    }

    attn_dots1<<<75000, 256, 0, stream>>>(h1, att1s, att1d, asrc1, adst1);
    edge_denom1<<<15625, 256, 0, stream>>>(edges, asrc1, adst1, denom1);

    // per-dst-type schedule: type -> (relations, slot indices, output slot)
    const int SRC[10] = {0,1,2,3,0,1,2,1,3,1};
    struct TypePlan { int t; int cnt; int rels[4]; int sl[4]; int outsl; };
    const TypePlan plan[4] = {
        {1, 4, {1,4,6,8}, {0,1,2,3}, 3},   // h1f[1] = slot3
        {2, 2, {2,7,0,0}, {0,1,0,0}, 1},   // h1f[2] = slot1
        {0, 2, {0,5,0,0}, {0,2,0,0}, 2},   // h1f[0] = slot2
        {3, 2, {3,9,0,0}, {0,4,0,0}, 4},   // h1f[3] = slot4
    };
    float* h1f[4];

    for (int p = 0; p < 4; ++p) {
        const TypePlan& tp = plan[p];
        // zero the agg slots this type uses
        for (int j = 0; j < tp.cnt; ++j)
            hipMemsetAsync(slot_p(tp.sl[j]), 0, SLOT * 4, stream);
        // scatter each relation into its slot
        for (int j = 0; j < tp.cnt; ++j) {
            int e = tp.rels[j];
            edge_msg1_rel<<<100000, 256, 0, stream>>>(
                edges + (long)e * 2 * NE,
                h1 + (long)SRC[e] * NN * 128,
                asrc1 + (long)e * NN * 8,
                adst1 + (long)e * NN * 8,
                denom1 + (long)e * NN * 8,
                slot_p(tp.sl[j]));
        }
        // tanh-colsum GEMM per relation
        for (int j = 0; j < tp.cnt; ++j) {
            int e = tp.rels[j];
            gemm_k<64><<<dim3(469, 2, 1), 256, 0, stream>>>(
                slot_p(tp.sl[j]), 0, k1W, 0, k1b, 0,
                colsum1 + (long)e * 128, 0, NN, 128, 128, 1, 1);
        }
        score_t_k<<<1, 32, 0, stream>>>(colsum1, q1, sattn1, 128, tp.t);
        fusion_t<<<3750, 256, 0, stream>>>(
            slot_p(tp.sl[0]), slot_p(tp.sl[1]),
            slot_p(tp.sl[tp.cnt > 2 ? 2 : 0]), slot_p(tp.sl[tp.cnt > 3 ? 3 : 0]),
            tp.cnt, tp.rels[0], tp.rels[1], tp.rels[2], tp.rels[3],
            sattn1, slot_p(tp.outsl));
        h1f[tp.t] = slot_p(tp.outsl);
    }

    // ---- layer 2 (h1 region is dead now; overlay) ----
    hipMemsetAsync(agg2, 0, 9600000L * 4, stream);
    hipMemsetAsync(denom2, 0, 300000L * 4, stream);

    for (int t = 0; t < 4; ++t) {
        gemm_k<32><<<dim3(469, 1, 1), 256, 0, stream>>>(
            h1f[t], 0, W2 + (long)t * 128 * 32, 0, b2 + t * 32, 0,
            h2 + (long)t * NN * 32, 0, NN, 128, 32, 0, 0);
    }

    attn_dots2<<<37500, 256, 0, stream>>>(h2, att2s, att2d, asrc2, adst2);
    edge_denom2<<<15625, 256, 0, stream>>>(edges, asrc2, adst2, denom2);
    edge_msg2<<<500000, 256, 0, stream>>>(edges, h2, asrc2, adst2, denom2, agg2);

    gemm_k<32><<<dim3(469, 1, 10), 256, 0, stream>>>(
        agg2, 960000L, k2W, 0, k2b, 0, colsum2, 32L, NN, 32, 32, 1, 1);
    score_all_k<<<1, 64, 0, stream>>>(colsum2, q2, sattn2, 32);
    final_softmax<<<15000, 256, 0, stream>>>(agg2, sattn2, (float*)d_out);
}

// Round 5
// 2529.535 us; speedup vs baseline: 2.5496x; 2.5496x over previous
//
#include <hip/hip_runtime.h>

#define NN 30000
#define NE 400000

__constant__ int d_SRC[10] = {0,1,2,3,0,1,2,1,3,1};
__constant__ int d_DST[10] = {0,1,2,3,1,0,1,2,1,3};

// ---------------- fp32 tiled GEMM: C[M,N] = act(A)[M,K] @ B[K,N] + bias ----
// epi=0: store C (fp32). epi=1: tanh + column-sum -> atomicAdd into C[N] (colsum).
template<int BN>
__global__ __launch_bounds__(256)
void gemm_k(const float* __restrict__ A, long sA,
            const float* __restrict__ B, long sB,
            const float* __restrict__ bias, long sBias,
            float* __restrict__ C, long sC,
            int M, int K, int N, int relu_a, int epi)
{
    constexpr int BM = 64, BK = 16;
    constexpr int TN = BN / 16;
    const int z = blockIdx.z;
    A += (long)z * sA;
    B += (long)z * sB;
    bias += (long)z * sBias;
    C += (long)z * sC;
    const int m0 = blockIdx.x * BM;
    const int n0 = blockIdx.y * BN;
    const int tid = threadIdx.x;

    __shared__ float As[BK][BM];
    __shared__ float Bs[BK][BN];

    const int ar = tid >> 2;
    const int ak = (tid & 3) << 2;
    const int bk = tid >> 4;
    const int bn = (tid & 15) * TN;
    const int tr = (tid >> 4) << 2;
    const int tc = (tid & 15) * TN;

    float acc[4][TN];
#pragma unroll
    for (int r = 0; r < 4; ++r)
#pragma unroll
        for (int j = 0; j < TN; ++j) acc[r][j] = 0.f;

    const int grow = m0 + ar;
    for (int k0 = 0; k0 < K; k0 += BK) {
        float av[4];
        if (grow < M) {
            const float* ap = A + (long)grow * K + k0 + ak;
            float4 u = *(const float4*)ap;
            av[0] = u.x; av[1] = u.y; av[2] = u.z; av[3] = u.w;
            if (relu_a) {
#pragma unroll
                for (int j = 0; j < 4; ++j) av[j] = fmaxf(av[j], 0.f);
            }
        } else {
            av[0] = av[1] = av[2] = av[3] = 0.f;
        }
        As[ak + 0][ar] = av[0]; As[ak + 1][ar] = av[1];
        As[ak + 2][ar] = av[2]; As[ak + 3][ar] = av[3];

        {
            const float* bp = B + (long)(k0 + bk) * N + n0 + bn;
            if constexpr (TN == 4) {
                float4 u = *(const float4*)bp;
                Bs[bk][bn + 0] = u.x; Bs[bk][bn + 1] = u.y;
                Bs[bk][bn + 2] = u.z; Bs[bk][bn + 3] = u.w;
            } else {
                float2 u = *(const float2*)bp;
                Bs[bk][bn + 0] = u.x; Bs[bk][bn + 1] = u.y;
            }
        }
        __syncthreads();
#pragma unroll
        for (int k = 0; k < BK; ++k) {
            float4 a4 = *(const float4*)&As[k][tr];
            float ar4[4] = {a4.x, a4.y, a4.z, a4.w};
            float bv[TN];
            if constexpr (TN == 4) {
                float4 b4 = *(const float4*)&Bs[k][tc];
                bv[0] = b4.x; bv[1] = b4.y; bv[2] = b4.z; bv[3] = b4.w;
            } else {
                float2 b2 = *(const float2*)&Bs[k][tc];
                bv[0] = b2.x; bv[1] = b2.y;
            }
#pragma unroll
            for (int r = 0; r < 4; ++r)
#pragma unroll
                for (int j = 0; j < TN; ++j)
                    acc[r][j] += ar4[r] * bv[j];
        }
        __syncthreads();
    }

    float biasv[TN];
#pragma unroll
    for (int j = 0; j < TN; ++j) biasv[j] = bias[n0 + tc + j];

    if (epi == 0) {
#pragma unroll
        for (int r = 0; r < 4; ++r) {
            int gr = m0 + tr + r;
            if (gr < M) {
                float* cp = C + (long)gr * N + n0 + tc;
#pragma unroll
                for (int j = 0; j < TN; ++j) cp[j] = acc[r][j] + biasv[j];
            }
        }
    } else {
        float cs[TN];
#pragma unroll
        for (int j = 0; j < TN; ++j) cs[j] = 0.f;
#pragma unroll
        for (int r = 0; r < 4; ++r) {
            int gr = m0 + tr + r;
            if (gr < M) {
#pragma unroll
                for (int j = 0; j < TN; ++j) cs[j] += tanhf(acc[r][j] + biasv[j]);
            }
        }
        float* red = &As[0][0];
#pragma unroll
        for (int j = 0; j < TN; ++j) red[(tid >> 4) * BN + tc + j] = cs[j];
        __syncthreads();
        if (tid < BN) {
            float s = 0.f;
            for (int t16 = 0; t16 < 16; ++t16) s += red[t16 * BN + tid];
            unsafeAtomicAdd(&C[n0 + tid], s);
        }
    }
}

// ---------------- CSR build ----------------
__global__ __launch_bounds__(256)
void csr_count(const int* __restrict__ edges, int* __restrict__ cnt)
{
    int idx = blockIdx.x * 256 + threadIdx.x;
    if (idx >= 10 * NE) return;
    int e = idx / NE;
    int i = idx - e * NE;
    int col = edges[(long)e * 2 * NE + NE + i];
    atomicAdd(&cnt[e * NN + col], 1);
}

// one block (1024 thr) per relation; cnt aliases cur (each thread reads only its own bins first)
__global__ __launch_bounds__(1024)
void csr_scan(int* __restrict__ cur, int* __restrict__ off)
{
    int e = blockIdx.x;
    int t = threadIdx.x;
    __shared__ int part[1024];
    const int CH = 30;  // 1024*30 >= 30000
    int base = t * CH;
    int loc[CH];
    int s = 0;
#pragma unroll
    for (int k = 0; k < CH; ++k) {
        int n = base + k;
        int v = (n < NN) ? cur[e * NN + n] : 0;
        loc[k] = s;
        s += v;
    }
    part[t] = s;
    __syncthreads();
    for (int d = 1; d < 1024; d <<= 1) {
        int v = (t >= d) ? part[t - d] : 0;
        __syncthreads();
        part[t] += v;
        __syncthreads();
    }
    int pre = (t == 0) ? 0 : part[t - 1];
#pragma unroll
    for (int k = 0; k < CH; ++k) {
        int n = base + k;
        if (n < NN) {
            int o = pre + loc[k];
            off[e * (NN + 1) + n] = o;
            cur[e * NN + n] = o;
        }
    }
    if (t == 1023) off[e * (NN + 1) + NN] = part[1023];
}

__global__ __launch_bounds__(256)
void csr_fill(const int* __restrict__ edges, int* __restrict__ cur,
              int* __restrict__ rows)
{
    int idx = blockIdx.x * 256 + threadIdx.x;
    if (idx >= 10 * NE) return;
    int e = idx / NE;
    int i = idx - e * NE;
    int row = edges[(long)e * 2 * NE + i];
    int col = edges[(long)e * 2 * NE + NE + i];
    int pos = atomicAdd(&cur[e * NN + col], 1);
    rows[(long)e * NE + pos] = row;
}

// ---------------- layer-1 attention dots: asrc/adst [10][NN][8] ----------------
__global__ __launch_bounds__(256)
void attn_dots1(const float* __restrict__ h1,
                const float* __restrict__ att_src,
                const float* __restrict__ att_dst,
                float* __restrict__ asrc, float* __restrict__ adst)
{
    int gid = blockIdx.x * 256 + threadIdx.x;
    int wave = gid >> 6;
    int lane = gid & 63;
    if (wave >= 10 * NN) return;
    int e = wave / NN;
    int n = wave - e * NN;
    int s = d_SRC[e], d = d_DST[e];
    float2 hs = *(const float2*)&h1[(long)(s * NN + n) * 128 + 2 * lane];
    float2 hd = *(const float2*)&h1[(long)(d * NN + n) * 128 + 2 * lane];
    float2 av = *(const float2*)&att_src[e * 128 + 2 * lane];
    float2 bv = *(const float2*)&att_dst[e * 128 + 2 * lane];
    float ps = hs.x * av.x + hs.y * av.y;
    float pd = hd.x * bv.x + hd.y * bv.y;
#pragma unroll
    for (int off = 1; off < 8; off <<= 1) {
        ps += __shfl_xor(ps, off, 64);
        pd += __shfl_xor(pd, off, 64);
    }
    if ((lane & 7) == 0) {
        int h = lane >> 3;
        asrc[(long)(e * NN + n) * 8 + h] = ps;
        adst[(long)(e * NN + n) * 8 + h] = pd;
    }
}

// ---------------- layer-1 gather-aggregate: one wave per dst node -------------
__global__ __launch_bounds__(256)
void gather_agg1(const int* __restrict__ off, const int* __restrict__ rows,
                 const float* __restrict__ asrc_e, const float* __restrict__ adst_e,
                 const float* __restrict__ h1s, float* __restrict__ slot)
{
    int node = blockIdx.x * 4 + (threadIdx.x >> 6);
    int lane = threadIdx.x & 63;
    if (node >= NN) return;
    int h = lane >> 3;
    int beg = off[node], end = off[node + 1];
    float ad = adst_e[node * 8 + h];
    float den = 1e-16f;
    for (int j = beg; j < end; ++j) {
        int r = rows[j];
        float a = asrc_e[r * 8 + h] + ad;
        a = a > 0.f ? a : 0.2f * a;
        den += __expf(a);
    }
    float2 acc = {0.f, 0.f};
    for (int j = beg; j < end; ++j) {
        int r = rows[j];
        float a = asrc_e[r * 8 + h] + ad;
        a = a > 0.f ? a : 0.2f * a;
        float w = __expf(a) / den;
        float2 hv = *(const float2*)&h1s[(long)r * 128 + 2 * lane];
        acc.x += w * hv.x;
        acc.y += w * hv.y;
    }
    *(float2*)&slot[(long)node * 128 + 2 * lane] = acc;
}

// ---------------- semantic score softmax for ONE dst type ----------------
__global__ void score_t_k(const float* __restrict__ colsum, const float* __restrict__ q,
                          float* __restrict__ sattn, int C, int t)
{
    __shared__ float sc[10];
    int tid = threadIdx.x;
    if (tid < 10) {
        if (d_DST[tid] == t) {
            float s = 0.f;
            for (int c = 0; c < C; ++c) s += q[c] * colsum[tid * C + c];
            sc[tid] = s / (float)NN;
        } else {
            sc[tid] = -1e30f;
        }
    }
    __syncthreads();
    if (tid == 0) {
        float mx = -1e30f;
        for (int m = 0; m < 10; ++m) if (d_DST[m] == t) mx = fmaxf(mx, sc[m]);
        float sum = 0.f;
        float ex[10];
        for (int m = 0; m < 10; ++m) {
            ex[m] = 0.f;
            if (d_DST[m] == t) { ex[m] = __expf(sc[m] - mx); sum += ex[m]; }
        }
        for (int m = 0; m < 10; ++m) if (d_DST[m] == t) sattn[m] = ex[m] / sum;
    }
}

// ---------------- per-type fusion: out = elu( sum_j sattn[r_j]*relu(slot_j) ) ---------
__global__ __launch_bounds__(256)
void fusion_t(const float* s0, const float* s1, const float* s2, const float* s3,
              int cnt, int r0, int r1, int r2, int r3,
              const float* __restrict__ sattn, float* __restrict__ out)
{
    int idx = blockIdx.x * 256 + threadIdx.x;
    if (idx >= NN * 32) return;
    int c4 = idx & 31;
    int n = idx >> 5;
    long off = (long)n * 128 + c4 * 4;
    const float* sl[4] = {s0, s1, s2, s3};
    int rl[4] = {r0, r1, r2, r3};
    float4 o = {0.f, 0.f, 0.f, 0.f};
    for (int j = 0; j < cnt; ++j) {
        float w = sattn[rl[j]];
        float4 v = *(const float4*)(sl[j] + off);
        o.x += w * fmaxf(v.x, 0.f);
        o.y += w * fmaxf(v.y, 0.f);
        o.z += w * fmaxf(v.z, 0.f);
        o.w += w * fmaxf(v.w, 0.f);
    }
    o.x = o.x > 0.f ? o.x : __expf(o.x) - 1.f;
    o.y = o.y > 0.f ? o.y : __expf(o.y) - 1.f;
    o.z = o.z > 0.f ? o.z : __expf(o.z) - 1.f;
    o.w = o.w > 0.f ? o.w : __expf(o.w) - 1.f;
    *(float4*)(out + off) = o;
}

// ---------------- layer-2 attention dots (1 head, 32 ch) ----------------
__global__ __launch_bounds__(256)
void attn_dots2(const float* __restrict__ h2,
                const float* __restrict__ att_src,
                const float* __restrict__ att_dst,
                float* __restrict__ asrc, float* __restrict__ adst)
{
    int gid = blockIdx.x * 256 + threadIdx.x;
    int p = gid >> 5;
    int l = gid & 31;
    if (p >= 10 * NN) return;
    int e = p / NN, n = p - e * NN;
    int s = d_SRC[e], d = d_DST[e];
    float hs = h2[(long)(s * NN + n) * 32 + l];
    float hd = h2[(long)(d * NN + n) * 32 + l];
    float ps = hs * att_src[e * 32 + l];
    float pd = hd * att_dst[e * 32 + l];
#pragma unroll
    for (int off = 1; off < 32; off <<= 1) {
        ps += __shfl_xor(ps, off, 64);
        pd += __shfl_xor(pd, off, 64);
    }
    if (l == 0) { asrc[e * NN + n] = ps; adst[e * NN + n] = pd; }
}

// ---------------- layer-2 gather-aggregate: 32 lanes per dst node, z = relation ------
__global__ __launch_bounds__(256)
void gather_agg2(const int* __restrict__ csr_off, const int* __restrict__ csr_rows,
                 const float* __restrict__ h2,
                 const float* __restrict__ asrc, const float* __restrict__ adst,
                 float* __restrict__ agg2)
{
    int e = blockIdx.y;
    int node = blockIdx.x * 8 + (threadIdx.x >> 5);
    int lane = threadIdx.x & 31;
    if (node >= NN) return;
    const int* off = csr_off + e * (NN + 1);
    const int* rows = csr_rows + (long)e * NE;
    const float* h2s = h2 + (long)d_SRC[e] * NN * 32;
    const float* as = asrc + e * NN;
    float ad = adst[e * NN + node];
    int beg = off[node], end = off[node + 1];
    float den = 1e-16f;
    for (int j = beg; j < end; ++j) {
        int r = rows[j];
        float a = as[r] + ad;
        a = a > 0.f ? a : 0.2f * a;
        den += __expf(a);
    }
    float acc = 0.f;
    for (int j = beg; j < end; ++j) {
        int r = rows[j];
        float a = as[r] + ad;
        a = a > 0.f ? a : 0.2f * a;
        float w = __expf(a) / den;
        acc += w * h2s[(long)r * 32 + lane];
    }
    agg2[((long)e * NN + node) * 32 + lane] = acc;
}

// ---------------- semantic score + softmax over ALL types (layer 2) ----------------
__global__ void score_all_k(const float* __restrict__ colsum, const float* __restrict__ q,
                            float* __restrict__ sattn, int C)
{
    __shared__ float sc[10];
    int tid = threadIdx.x;
    if (tid < 10) {
        float s = 0.f;
        for (int c = 0; c < C; ++c) s += q[c] * colsum[tid * C + c];
        sc[tid] = s / (float)NN;
    }
    __syncthreads();
    if (tid < 4) {
        float mx = -1e30f;
        for (int m = 0; m < 10; ++m) if (d_DST[m] == tid) mx = fmaxf(mx, sc[m]);
        float ex[10];
        float sum = 0.f;
        for (int m = 0; m < 10; ++m) {
            ex[m] = 0.f;
            if (d_DST[m] == tid) { ex[m] = __expf(sc[m] - mx); sum += ex[m]; }
        }
        for (int m = 0; m < 10; ++m) if (d_DST[m] == tid) sattn[m] = ex[m] / sum;
    }
}

// ---------------- final: per-node channel softmax, fp32 out ----------------
__global__ __launch_bounds__(256)
void final_softmax(const float* __restrict__ agg, const float* __restrict__ sattn,
                   float* __restrict__ out)
{
    int gid = blockIdx.x * 256 + threadIdx.x;
    int c = gid & 31;
    int p = gid >> 5;
    if (p >= 4 * NN) return;
    int t = p / NN, n = p - t * NN;
    float f = 0.f;
    for (int m = 0; m < 10; ++m) {
        if (d_DST[m] != t) continue;
        f += sattn[m] * fmaxf(agg[(long)(m * NN + n) * 32 + c], 0.f);
    }
    float mx = f;
#pragma unroll
    for (int off = 1; off < 32; off <<= 1) mx = fmaxf(mx, __shfl_xor(mx, off, 64));
    float ex = __expf(f - mx);
    float sm = ex;
#pragma unroll
    for (int off = 1; off < 32; off <<= 1) sm += __shfl_xor(sm, off, 64);
    out[(long)(t * NN + n) * 32 + c] = ex / sm;
}

extern "C" void kernel_launch(void* const* d_in, const int* in_sizes, int n_in,
                              void* d_out, int out_size, void* d_ws, size_t ws_size,
                              hipStream_t stream) {
    const float* x[4] = {
        (const float*)d_in[0], (const float*)d_in[1],
        (const float*)d_in[2], (const float*)d_in[3]};
    const int* edges = (const int*)d_in[4];
    const float* W1    = (const float*)d_in[5];
    const float* b1    = (const float*)d_in[6];
    const float* att1s = (const float*)d_in[7];
    const float* att1d = (const float*)d_in[8];
    const float* k1W   = (const float*)d_in[9];
    const float* k1b   = (const float*)d_in[10];
    const float* q1    = (const float*)d_in[11];
    const float* W2    = (const float*)d_in[12];
    const float* b2    = (const float*)d_in[13];
    const float* att2s = (const float*)d_in[14];
    const float* att2d = (const float*)d_in[15];
    const float* k2W   = (const float*)d_in[16];
    const float* k2b   = (const float*)d_in[17];
    const float* q2    = (const float*)d_in[18];

    // ---- workspace layout (floats), peak ~176 MB ----
    float* W = (float*)d_ws;
    float* h1      = W;                      // 15,360,000 (layer-2 overlays here later)
    float* slots   = W + 15360000;           // 5 x 3,840,000 = 19,200,000
    float* asrc1   = W + 34560000;           //  2,400,000
    float* adst1   = W + 36960000;           //  2,400,000
    float* colsum1 = W + 39360000;           //      1,280
    float* sattn1  = W + 39361280;           //         16
    float* colsum2 = W + 39361296;           //        320
    float* sattn2  = W + 39361616;           //         16
    int*   csr_off = (int*)(W + 39361640);   //    300,010 ints
    int*   csr_cur = csr_off + 300016;       //    300,000 ints
    int*   csr_row = csr_cur + 300000;       //  4,000,000 ints
    // layer-2 overlay into h1's region (h1 dead after layer-1 gathers):
    float* h2      = h1;                     //  3,840,000
    float* agg2    = h1 + 3840000;           //  9,600,000
    float* asrc2   = h1 + 13440000;          //    300,000
    float* adst2   = h1 + 13740000;          //    300,000

    const long SLOT = 3840000;  // NN*128
    auto slot_p = [&](int i) { return slots + (long)i * SLOT; };

    // ---- CSR build (edges only; reused by both layers) ----
    hipMemsetAsync(csr_cur, 0, 300000L * 4, stream);
    csr_count<<<15625, 256, 0, stream>>>(edges, csr_cur);
    csr_scan<<<10, 1024, 0, stream>>>(csr_cur, csr_off);
    csr_fill<<<15625, 256, 0, stream>>>(edges, csr_cur, csr_row);

    hipMemsetAsync(colsum1, 0, 1632L * 4, stream);

    // layer-1 projection: h1[t] = x[t] @ W1[t] + b1[t]
    for (int t = 0; t < 4; ++t) {
        gemm_k<64><<<dim3(469, 2, 1), 256, 0, stream>>>(
            x[t], 0, W1 + (long)t * 256 * 128, 0, b1 + t * 128, 0,
            h1 + (long)t * NN * 128, 0, NN, 256, 128, 0, 0);
    }

    attn_dots1<<<75000, 256, 0, stream>>>(h1, att1s, att1d, asrc1, adst1);

    // per-dst-type schedule
    const int SRC[10] = {0,1,2,3,0,1,2,1,3,1};
    struct TypePlan { int t; int cnt; int rels[4]; int sl[4]; int outsl; };
    const TypePlan plan[4] = {
        {1, 4, {1,4,6,8}, {0,1,2,3}, 3},   // h1f[1] = slot3
        {2, 2, {2,7,0,0}, {0,1,0,0}, 1},   // h1f[2] = slot1
        {0, 2, {0,5,0,0}, {0,2,0,0}, 2},   // h1f[0] = slot2
        {3, 2, {3,9,0,0}, {0,4,0,0}, 4},   // h1f[3] = slot4
    };
    float* h1f[4];

    for (int p = 0; p < 4; ++p) {
        const TypePlan& tp = plan[p];
        for (int j = 0; j < tp.cnt; ++j) {
            int e = tp.rels[j];
            gather_agg1<<<7500, 256, 0, stream>>>(
                csr_off + e * (NN + 1), csr_row + (long)e * NE,
                asrc1 + (long)e * NN * 8, adst1 + (long)e * NN * 8,
                h1 + (long)SRC[e] * NN * 128, slot_p(tp.sl[j]));
        }
        for (int j = 0; j < tp.cnt; ++j) {
            int e = tp.rels[j];
            gemm_k<64><<<dim3(469, 2, 1), 256, 0, stream>>>(
                slot_p(tp.sl[j]), 0, k1W, 0, k1b, 0,
                colsum1 + (long)e * 128, 0, NN, 128, 128, 1, 1);
        }
        score_t_k<<<1, 32, 0, stream>>>(colsum1, q1, sattn1, 128, tp.t);
        fusion_t<<<3750, 256, 0, stream>>>(
            slot_p(tp.sl[0]), slot_p(tp.sl[1]),
            slot_p(tp.sl[tp.cnt > 2 ? 2 : 0]), slot_p(tp.sl[tp.cnt > 3 ? 3 : 0]),
            tp.cnt, tp.rels[0], tp.rels[1], tp.rels[2], tp.rels[3],
            sattn1, slot_p(tp.outsl));
        h1f[tp.t] = slot_p(tp.outsl);
    }

    // ---- layer 2 (h1 region is dead now; overlay) ----
    for (int t = 0; t < 4; ++t) {
        gemm_k<32><<<dim3(469, 1, 1), 256, 0, stream>>>(
            h1f[t], 0, W2 + (long)t * 128 * 32, 0, b2 + t * 32, 0,
            h2 + (long)t * NN * 32, 0, NN, 128, 32, 0, 0);
    }

    attn_dots2<<<37500, 256, 0, stream>>>(h2, att2s, att2d, asrc2, adst2);
    gather_agg2<<<dim3(3750, 10), 256, 0, stream>>>(
        csr_off, csr_row, h2, asrc2, adst2, agg2);

    gemm_k<32><<<dim3(469, 1, 10), 256, 0, stream>>>(
        agg2, 960000L, k2W, 0, k2b, 0, colsum2, 32L, NN, 32, 32, 1, 1);
    score_all_k<<<1, 64, 0, stream>>>(colsum2, q2, sattn2, 32);
    final_softmax<<<15000, 256, 0, stream>>>(agg2, sattn2, (float*)d_out);
}

// Round 6
// 1818.942 us; speedup vs baseline: 3.5457x; 1.3907x over previous
//
#include <hip/hip_runtime.h>

#define NN 30000
#define NE 400000

__constant__ int d_SRC[10] = {0,1,2,3,0,1,2,1,3,1};
__constant__ int d_DST[10] = {0,1,2,3,1,0,1,2,1,3};

// ---------------- fp32 tiled GEMM: C[M,N] = act(A)[M,K] @ B[K,N] + bias ----
// epi=0: store C (fp32). epi=1: tanh + column-sum -> atomicAdd into C[N] (colsum).
template<int BN>
__global__ __launch_bounds__(256)
void gemm_k(const float* __restrict__ A, long sA,
            const float* __restrict__ B, long sB,
            const float* __restrict__ bias, long sBias,
            float* __restrict__ C, long sC,
            int M, int K, int N, int relu_a, int epi)
{
    constexpr int BM = 64, BK = 16;
    constexpr int TN = BN / 16;
    const int z = blockIdx.z;
    A += (long)z * sA;
    B += (long)z * sB;
    bias += (long)z * sBias;
    C += (long)z * sC;
    const int m0 = blockIdx.x * BM;
    const int n0 = blockIdx.y * BN;
    const int tid = threadIdx.x;

    __shared__ float As[BK][BM];
    __shared__ float Bs[BK][BN];

    const int ar = tid >> 2;
    const int ak = (tid & 3) << 2;
    const int bk = tid >> 4;
    const int bn = (tid & 15) * TN;
    const int tr = (tid >> 4) << 2;
    const int tc = (tid & 15) * TN;

    float acc[4][TN];
#pragma unroll
    for (int r = 0; r < 4; ++r)
#pragma unroll
        for (int j = 0; j < TN; ++j) acc[r][j] = 0.f;

    const int grow = m0 + ar;
    for (int k0 = 0; k0 < K; k0 += BK) {
        float av[4];
        if (grow < M) {
            const float* ap = A + (long)grow * K + k0 + ak;
            float4 u = *(const float4*)ap;
            av[0] = u.x; av[1] = u.y; av[2] = u.z; av[3] = u.w;
            if (relu_a) {
#pragma unroll
                for (int j = 0; j < 4; ++j) av[j] = fmaxf(av[j], 0.f);
            }
        } else {
            av[0] = av[1] = av[2] = av[3] = 0.f;
        }
        As[ak + 0][ar] = av[0]; As[ak + 1][ar] = av[1];
        As[ak + 2][ar] = av[2]; As[ak + 3][ar] = av[3];

        {
            const float* bp = B + (long)(k0 + bk) * N + n0 + bn;
            if constexpr (TN == 4) {
                float4 u = *(const float4*)bp;
                Bs[bk][bn + 0] = u.x; Bs[bk][bn + 1] = u.y;
                Bs[bk][bn + 2] = u.z; Bs[bk][bn + 3] = u.w;
            } else {
                float2 u = *(const float2*)bp;
                Bs[bk][bn + 0] = u.x; Bs[bk][bn + 1] = u.y;
            }
        }
        __syncthreads();
#pragma unroll
        for (int k = 0; k < BK; ++k) {
            float4 a4 = *(const float4*)&As[k][tr];
            float ar4[4] = {a4.x, a4.y, a4.z, a4.w};
            float bv[TN];
            if constexpr (TN == 4) {
                float4 b4 = *(const float4*)&Bs[k][tc];
                bv[0] = b4.x; bv[1] = b4.y; bv[2] = b4.z; bv[3] = b4.w;
            } else {
                float2 b2 = *(const float2*)&Bs[k][tc];
                bv[0] = b2.x; bv[1] = b2.y;
            }
#pragma unroll
            for (int r = 0; r < 4; ++r)
#pragma unroll
                for (int j = 0; j < TN; ++j)
                    acc[r][j] += ar4[r] * bv[j];
        }
        __syncthreads();
    }

    float biasv[TN];
#pragma unroll
    for (int j = 0; j < TN; ++j) biasv[j] = bias[n0 + tc + j];

    if (epi == 0) {
#pragma unroll
        for (int r = 0; r < 4; ++r) {
            int gr = m0 + tr + r;
            if (gr < M) {
                float* cp = C + (long)gr * N + n0 + tc;
#pragma unroll
                for (int j = 0; j < TN; ++j) cp[j] = acc[r][j] + biasv[j];
            }
        }
    } else {
        float cs[TN];
#pragma unroll
        for (int j = 0; j < TN; ++j) cs[j] = 0.f;
#pragma unroll
        for (int r = 0; r < 4; ++r) {
            int gr = m0 + tr + r;
            if (gr < M) {
#pragma unroll
                for (int j = 0; j < TN; ++j) cs[j] += tanhf(acc[r][j] + biasv[j]);
            }
        }
        float* red = &As[0][0];
#pragma unroll
        for (int j = 0; j < TN; ++j) red[(tid >> 4) * BN + tc + j] = cs[j];
        __syncthreads();
        if (tid < BN) {
            float s = 0.f;
            for (int t16 = 0; t16 < 16; ++t16) s += red[t16 * BN + tid];
            unsafeAtomicAdd(&C[n0 + tid], s);
        }
    }
}

// ---------------- CSR build ----------------
__global__ __launch_bounds__(256)
void csr_count(const int* __restrict__ edges, int* __restrict__ cnt)
{
    int idx = blockIdx.x * 256 + threadIdx.x;
    if (idx >= 10 * NE) return;
    int e = idx / NE;
    int i = idx - e * NE;
    int col = edges[(long)e * 2 * NE + NE + i];
    atomicAdd(&cnt[e * NN + col], 1);
}

__global__ __launch_bounds__(1024)
void csr_scan(int* __restrict__ cur, int* __restrict__ off)
{
    int e = blockIdx.x;
    int t = threadIdx.x;
    __shared__ int part[1024];
    const int CH = 30;
    int base = t * CH;
    int loc[CH];
    int s = 0;
#pragma unroll
    for (int k = 0; k < CH; ++k) {
        int n = base + k;
        int v = (n < NN) ? cur[e * NN + n] : 0;
        loc[k] = s;
        s += v;
    }
    part[t] = s;
    __syncthreads();
    for (int d = 1; d < 1024; d <<= 1) {
        int v = (t >= d) ? part[t - d] : 0;
        __syncthreads();
        part[t] += v;
        __syncthreads();
    }
    int pre = (t == 0) ? 0 : part[t - 1];
#pragma unroll
    for (int k = 0; k < CH; ++k) {
        int n = base + k;
        if (n < NN) {
            int o = pre + loc[k];
            off[e * (NN + 1) + n] = o;
            cur[e * NN + n] = o;
        }
    }
    if (t == 1023) off[e * (NN + 1) + NN] = part[1023];
}

__global__ __launch_bounds__(256)
void csr_fill(const int* __restrict__ edges, int* __restrict__ cur,
              int* __restrict__ rows)
{
    int idx = blockIdx.x * 256 + threadIdx.x;
    if (idx >= 10 * NE) return;
    int e = idx / NE;
    int i = idx - e * NE;
    int row = edges[(long)e * 2 * NE + i];
    int col = edges[(long)e * 2 * NE + NE + i];
    int pos = atomicAdd(&cur[e * NN + col], 1);
    rows[(long)e * NE + pos] = row;
}

// ---------------- layer-1 attention dots: one pass over node types ----------------
__global__ __launch_bounds__(256)
void attn_dots1(const float* __restrict__ h1,
                const float* __restrict__ att_src,
                const float* __restrict__ att_dst,
                float* __restrict__ asrc, float* __restrict__ adst)
{
    int gid = blockIdx.x * 256 + threadIdx.x;
    int wave = gid >> 6;
    int lane = gid & 63;
    if (wave >= 4 * NN) return;
    int t = wave / NN;
    int n = wave - t * NN;
    float2 hv = *(const float2*)&h1[(long)(t * NN + n) * 128 + 2 * lane];
    const int SRCc[10] = {0,1,2,3,0,1,2,1,3,1};
    const int DSTc[10] = {0,1,2,3,1,0,1,2,1,3};
#pragma unroll
    for (int e = 0; e < 10; ++e) {
        if (SRCc[e] == t) {
            float2 av = *(const float2*)&att_src[e * 128 + 2 * lane];
            float p = hv.x * av.x + hv.y * av.y;
#pragma unroll
            for (int off = 1; off < 8; off <<= 1) p += __shfl_xor(p, off, 64);
            if ((lane & 7) == 0) asrc[(long)(e * NN + n) * 8 + (lane >> 3)] = p;
        }
        if (DSTc[e] == t) {
            float2 bv = *(const float2*)&att_dst[e * 128 + 2 * lane];
            float p = hv.x * bv.x + hv.y * bv.y;
#pragma unroll
            for (int off = 1; off < 8; off <<= 1) p += __shfl_xor(p, off, 64);
            if ((lane & 7) == 0) adst[(long)(e * NN + n) * 8 + (lane >> 3)] = p;
        }
    }
}

// ---------------- layer-1 gather-aggregate: SINGLE PASS, one wave per dst node -------
// agg = (sum_j ex_j * h_j) / (1e-16 + sum_j ex_j)
__global__ __launch_bounds__(256)
void gather_agg1(const int* __restrict__ off, const int* __restrict__ rows,
                 const float* __restrict__ asrc_e, const float* __restrict__ adst_e,
                 const float* __restrict__ h1s, float* __restrict__ slot)
{
    int node = blockIdx.x * 4 + (threadIdx.x >> 6);
    int lane = threadIdx.x & 63;
    if (node >= NN) return;
    int h = lane >> 3;
    int beg = off[node], end = off[node + 1];
    float ad = adst_e[node * 8 + h];
    float den = 1e-16f;
    float accx = 0.f, accy = 0.f;
    int j = beg;
    for (; j + 1 < end; j += 2) {
        int r0 = rows[j];
        int r1 = rows[j + 1];
        float a0 = asrc_e[r0 * 8 + h] + ad;
        float a1 = asrc_e[r1 * 8 + h] + ad;
        a0 = a0 > 0.f ? a0 : 0.2f * a0;
        a1 = a1 > 0.f ? a1 : 0.2f * a1;
        float e0 = __expf(a0);
        float e1 = __expf(a1);
        float2 h0 = *(const float2*)&h1s[(long)r0 * 128 + 2 * lane];
        float2 h1v = *(const float2*)&h1s[(long)r1 * 128 + 2 * lane];
        den += e0 + e1;
        accx += e0 * h0.x + e1 * h1v.x;
        accy += e0 * h0.y + e1 * h1v.y;
    }
    if (j < end) {
        int r0 = rows[j];
        float a0 = asrc_e[r0 * 8 + h] + ad;
        a0 = a0 > 0.f ? a0 : 0.2f * a0;
        float e0 = __expf(a0);
        float2 h0 = *(const float2*)&h1s[(long)r0 * 128 + 2 * lane];
        den += e0;
        accx += e0 * h0.x;
        accy += e0 * h0.y;
    }
    float inv = 1.0f / den;
    float2 o = {accx * inv, accy * inv};
    *(float2*)&slot[(long)node * 128 + 2 * lane] = o;
}

// ---------------- semantic score softmax for ONE dst type ----------------
__global__ void score_t_k(const float* __restrict__ colsum, const float* __restrict__ q,
                          float* __restrict__ sattn, int C, int t)
{
    __shared__ float sc[10];
    int tid = threadIdx.x;
    if (tid < 10) {
        if (d_DST[tid] == t) {
            float s = 0.f;
            for (int c = 0; c < C; ++c) s += q[c] * colsum[tid * C + c];
            sc[tid] = s / (float)NN;
        } else {
            sc[tid] = -1e30f;
        }
    }
    __syncthreads();
    if (tid == 0) {
        float mx = -1e30f;
        for (int m = 0; m < 10; ++m) if (d_DST[m] == t) mx = fmaxf(mx, sc[m]);
        float sum = 0.f;
        float ex[10];
        for (int m = 0; m < 10; ++m) {
            ex[m] = 0.f;
            if (d_DST[m] == t) { ex[m] = __expf(sc[m] - mx); sum += ex[m]; }
        }
        for (int m = 0; m < 10; ++m) if (d_DST[m] == t) sattn[m] = ex[m] / sum;
    }
}

// ---------------- per-type fusion: out = elu( sum_j sattn[r_j]*relu(slot_j) ) ---------
__global__ __launch_bounds__(256)
void fusion_t(const float* s0, const float* s1, const float* s2, const float* s3,
              int cnt, int r0, int r1, int r2, int r3,
              const float* __restrict__ sattn, float* __restrict__ out)
{
    int idx = blockIdx.x * 256 + threadIdx.x;
    if (idx >= NN * 32) return;
    int c4 = idx & 31;
    int n = idx >> 5;
    long off = (long)n * 128 + c4 * 4;
    const float* sl[4] = {s0, s1, s2, s3};
    int rl[4] = {r0, r1, r2, r3};
    float4 o = {0.f, 0.f, 0.f, 0.f};
    for (int j = 0; j < cnt; ++j) {
        float w = sattn[rl[j]];
        float4 v = *(const float4*)(sl[j] + off);
        o.x += w * fmaxf(v.x, 0.f);
        o.y += w * fmaxf(v.y, 0.f);
        o.z += w * fmaxf(v.z, 0.f);
        o.w += w * fmaxf(v.w, 0.f);
    }
    o.x = o.x > 0.f ? o.x : __expf(o.x) - 1.f;
    o.y = o.y > 0.f ? o.y : __expf(o.y) - 1.f;
    o.z = o.z > 0.f ? o.z : __expf(o.z) - 1.f;
    o.w = o.w > 0.f ? o.w : __expf(o.w) - 1.f;
    *(float4*)(out + off) = o;
}

// ---------------- layer-2 attention dots (1 head, 32 ch) ----------------
__global__ __launch_bounds__(256)
void attn_dots2(const float* __restrict__ h2,
                const float* __restrict__ att_src,
                const float* __restrict__ att_dst,
                float* __restrict__ asrc, float* __restrict__ adst)
{
    int gid = blockIdx.x * 256 + threadIdx.x;
    int p = gid >> 5;
    int l = gid & 31;
    if (p >= 10 * NN) return;
    int e = p / NN, n = p - e * NN;
    int s = d_SRC[e], d = d_DST[e];
    float hs = h2[(long)(s * NN + n) * 32 + l];
    float hd = h2[(long)(d * NN + n) * 32 + l];
    float ps = hs * att_src[e * 32 + l];
    float pd = hd * att_dst[e * 32 + l];
#pragma unroll
    for (int off = 1; off < 32; off <<= 1) {
        ps += __shfl_xor(ps, off, 64);
        pd += __shfl_xor(pd, off, 64);
    }
    if (l == 0) { asrc[e * NN + n] = ps; adst[e * NN + n] = pd; }
}

// ---------------- layer-2 gather-aggregate: SINGLE PASS, 32 lanes per node ----------
__global__ __launch_bounds__(256)
void gather_agg2(const int* __restrict__ csr_off, const int* __restrict__ csr_rows,
                 const float* __restrict__ h2,
                 const float* __restrict__ asrc, const float* __restrict__ adst,
                 float* __restrict__ agg2)
{
    int e = blockIdx.y;
    int node = blockIdx.x * 8 + (threadIdx.x >> 5);
    int lane = threadIdx.x & 31;
    if (node >= NN) return;
    const int* off = csr_off + e * (NN + 1);
    const int* rows = csr_rows + (long)e * NE;
    const float* h2s = h2 + (long)d_SRC[e] * NN * 32;
    const float* as = asrc + e * NN;
    float ad = adst[e * NN + node];
    int beg = off[node], end = off[node + 1];
    float den = 1e-16f;
    float acc = 0.f;
    int j = beg;
    for (; j + 1 < end; j += 2) {
        int r0 = rows[j];
        int r1 = rows[j + 1];
        float a0 = as[r0] + ad;
        float a1 = as[r1] + ad;
        a0 = a0 > 0.f ? a0 : 0.2f * a0;
        a1 = a1 > 0.f ? a1 : 0.2f * a1;
        float e0 = __expf(a0);
        float e1 = __expf(a1);
        float v0 = h2s[(long)r0 * 32 + lane];
        float v1 = h2s[(long)r1 * 32 + lane];
        den += e0 + e1;
        acc += e0 * v0 + e1 * v1;
    }
    if (j < end) {
        int r0 = rows[j];
        float a0 = as[r0] + ad;
        a0 = a0 > 0.f ? a0 : 0.2f * a0;
        float e0 = __expf(a0);
        den += e0;
        acc += e0 * h2s[(long)r0 * 32 + lane];
    }
    agg2[((long)e * NN + node) * 32 + lane] = acc / den;
}

// ---------------- semantic score + softmax over ALL types (layer 2) ----------------
__global__ void score_all_k(const float* __restrict__ colsum, const float* __restrict__ q,
                            float* __restrict__ sattn, int C)
{
    __shared__ float sc[10];
    int tid = threadIdx.x;
    if (tid < 10) {
        float s = 0.f;
        for (int c = 0; c < C; ++c) s += q[c] * colsum[tid * C + c];
        sc[tid] = s / (float)NN;
    }
    __syncthreads();
    if (tid < 4) {
        float mx = -1e30f;
        for (int m = 0; m < 10; ++m) if (d_DST[m] == tid) mx = fmaxf(mx, sc[m]);
        float ex[10];
        float sum = 0.f;
        for (int m = 0; m < 10; ++m) {
            ex[m] = 0.f;
            if (d_DST[m] == tid) { ex[m] = __expf(sc[m] - mx); sum += ex[m]; }
        }
        for (int m = 0; m < 10; ++m) if (d_DST[m] == tid) sattn[m] = ex[m] / sum;
    }
}

// ---------------- final: per-node channel softmax, fp32 out ----------------
__global__ __launch_bounds__(256)
void final_softmax(const float* __restrict__ agg, const float* __restrict__ sattn,
                   float* __restrict__ out)
{
    int gid = blockIdx.x * 256 + threadIdx.x;
    int c = gid & 31;
    int p = gid >> 5;
    if (p >= 4 * NN) return;
    int t = p / NN, n = p - t * NN;
    float f = 0.f;
    for (int m = 0; m < 10; ++m) {
        if (d_DST[m] != t) continue;
        f += sattn[m] * fmaxf(agg[(long)(m * NN + n) * 32 + c], 0.f);
    }
    float mx = f;
#pragma unroll
    for (int off = 1; off < 32; off <<= 1) mx = fmaxf(mx, __shfl_xor(mx, off, 64));
    float ex = __expf(f - mx);
    float sm = ex;
#pragma unroll
    for (int off = 1; off < 32; off <<= 1) sm += __shfl_xor(sm, off, 64);
    out[(long)(t * NN + n) * 32 + c] = ex / sm;
}

extern "C" void kernel_launch(void* const* d_in, const int* in_sizes, int n_in,
                              void* d_out, int out_size, void* d_ws, size_t ws_size,
                              hipStream_t stream) {
    const float* x[4] = {
        (const float*)d_in[0], (const float*)d_in[1],
        (const float*)d_in[2], (const float*)d_in[3]};
    const int* edges = (const int*)d_in[4];
    const float* W1    = (const float*)d_in[5];
    const float* b1    = (const float*)d_in[6];
    const float* att1s = (const float*)d_in[7];
    const float* att1d = (const float*)d_in[8];
    const float* k1W   = (const float*)d_in[9];
    const float* k1b   = (const float*)d_in[10];
    const float* q1    = (const float*)d_in[11];
    const float* W2    = (const float*)d_in[12];
    const float* b2    = (const float*)d_in[13];
    const float* att2s = (const float*)d_in[14];
    const float* att2d = (const float*)d_in[15];
    const float* k2W   = (const float*)d_in[16];
    const float* k2b   = (const float*)d_in[17];
    const float* q2    = (const float*)d_in[18];

    // ---- workspace layout (floats), peak ~176 MB ----
    float* W = (float*)d_ws;
    float* h1      = W;                      // 15,360,000 (layer-2 overlays here later)
    float* slots   = W + 15360000;           // 5 x 3,840,000 = 19,200,000
    float* asrc1   = W + 34560000;           //  2,400,000
    float* adst1   = W + 36960000;           //  2,400,000
    float* colsum1 = W + 39360000;           //      1,280
    float* sattn1  = W + 39361280;           //         16
    float* colsum2 = W + 39361296;           //        320
    float* sattn2  = W + 39361616;           //         16
    int*   csr_off = (int*)(W + 39361640);   //    300,010 ints
    int*   csr_cur = csr_off + 300016;       //    300,000 ints
    int*   csr_row = csr_cur + 300000;       //  4,000,000 ints
    // layer-2 overlay into h1's region (h1 dead after layer-1 gathers):
    float* h2      = h1;                     //  3,840,000
    float* agg2    = h1 + 3840000;           //  9,600,000
    float* asrc2   = h1 + 13440000;          //    300,000
    float* adst2   = h1 + 13740000;          //    300,000

    const long SLOT = 3840000;  // NN*128
    auto slot_p = [&](int i) { return slots + (long)i * SLOT; };

    // ---- CSR build (edges only; reused by both layers) ----
    hipMemsetAsync(csr_cur, 0, 300000L * 4, stream);
    csr_count<<<15625, 256, 0, stream>>>(edges, csr_cur);
    csr_scan<<<10, 1024, 0, stream>>>(csr_cur, csr_off);
    csr_fill<<<15625, 256, 0, stream>>>(edges, csr_cur, csr_row);

    hipMemsetAsync(colsum1, 0, 1632L * 4, stream);

    // layer-1 projection: h1[t] = x[t] @ W1[t] + b1[t]
    for (int t = 0; t < 4; ++t) {
        gemm_k<64><<<dim3(469, 2, 1), 256, 0, stream>>>(
            x[t], 0, W1 + (long)t * 256 * 128, 0, b1 + t * 128, 0,
            h1 + (long)t * NN * 128, 0, NN, 256, 128, 0, 0);
    }

    attn_dots1<<<30000, 256, 0, stream>>>(h1, att1s, att1d, asrc1, adst1);

    // per-dst-type schedule
    const int SRC[10] = {0,1,2,3,0,1,2,1,3,1};
    struct TypePlan { int t; int cnt; int rels[4]; int sl[4]; int outsl; };
    const TypePlan plan[4] = {
        {1, 4, {1,4,6,8}, {0,1,2,3}, 3},   // h1f[1] = slot3
        {2, 2, {2,7,0,0}, {0,1,0,0}, 1},   // h1f[2] = slot1
        {0, 2, {0,5,0,0}, {0,2,0,0}, 2},   // h1f[0] = slot2
        {3, 2, {3,9,0,0}, {0,4,0,0}, 4},   // h1f[3] = slot4
    };
    float* h1f[4];

    for (int p = 0; p < 4; ++p) {
        const TypePlan& tp = plan[p];
        for (int j = 0; j < tp.cnt; ++j) {
            int e = tp.rels[j];
            gather_agg1<<<7500, 256, 0, stream>>>(
                csr_off + e * (NN + 1), csr_row + (long)e * NE,
                asrc1 + (long)e * NN * 8, adst1 + (long)e * NN * 8,
                h1 + (long)SRC[e] * NN * 128, slot_p(tp.sl[j]));
        }
        for (int j = 0; j < tp.cnt; ++j) {
            int e = tp.rels[j];
            gemm_k<64><<<dim3(469, 2, 1), 256, 0, stream>>>(
                slot_p(tp.sl[j]), 0, k1W, 0, k1b, 0,
                colsum1 + (long)e * 128, 0, NN, 128, 128, 1, 1);
        }
        score_t_k<<<1, 32, 0, stream>>>(colsum1, q1, sattn1, 128, tp.t);
        fusion_t<<<3750, 256, 0, stream>>>(
            slot_p(tp.sl[0]), slot_p(tp.sl[1]),
            slot_p(tp.sl[tp.cnt > 2 ? 2 : 0]), slot_p(tp.sl[tp.cnt > 3 ? 3 : 0]),
            tp.cnt, tp.rels[0], tp.rels[1], tp.rels[2], tp.rels[3],
            sattn1, slot_p(tp.outsl));
        h1f[tp.t] = slot_p(tp.outsl);
    }

    // ---- layer 2 (h1 region is dead now; overlay) ----
    for (int t = 0; t < 4; ++t) {
        gemm_k<32><<<dim3(469, 1, 1), 256, 0, stream>>>(
            h1f[t], 0, W2 + (long)t * 128 * 32, 0, b2 + t * 32, 0,
            h2 + (long)t * NN * 32, 0, NN, 128, 32, 0, 0);
    }

    attn_dots2<<<37500, 256, 0, stream>>>(h2, att2s, att2d, asrc2, adst2);
    gather_agg2<<<dim3(3750, 10), 256, 0, stream>>>(
        csr_off, csr_row, h2, asrc2, adst2, agg2);

    gemm_k<32><<<dim3(469, 1, 10), 256, 0, stream>>>(
        agg2, 960000L, k2W, 0, k2b, 0, colsum2, 32L, NN, 32, 32, 1, 1);
    score_all_k<<<1, 64, 0, stream>>>(colsum2, q2, sattn2, 32);
    final_softmax<<<15000, 256, 0, stream>>>(agg2, sattn2, (float*)d_out);
}